// Round 6
// baseline (168.491 us; speedup 1.0000x reference)
//
#include <hip/hip_runtime.h>
#include <hip/hip_bf16.h>
#include <type_traits>

// out[b] = X[b] @ (X[b]^T @ X[b]);  B=8, S=4096, D=512, fp32 in/out.
// Pipeline (bf16 MFMA, fp32 accumulate), ws = 268MB observed:
//   k1: Xt[d][s] bf16 -> d_out[0:33.5M) ; Xb16[s][d] bf16 (octet-swizzled
//       per 64-d window: oct ^= s&7) -> ws+4.2M
//   k2: split-K=8 gram partials bf16, upper-triangle tiles only (symmetry),
//       XCD-swizzled, LDS dbuf (proven 2-phase gemm_bt) -> ws+37.7M
//   kr: reduce 8 bf16 partials -> full bf16 gram via LDS-transpose mirror;
//       gram stored octet-swizzled (oct ^= row&7 per 64-col window) for k3.
//   k3 (round 6): B-panel-RESIDENT GEMM. gram is tiny (512KB/batch), so a
//       block's whole B-panel (128 rows x K=512 = 128KB) lives in LDS for
//       the entire K-loop; only A streams (single-dbuf, counted vmcnt(2),
//       never 0 mid-loop). LDS = 128KB B + 32KB A-dbuf = 160KB (gfx950 max;
//       128KB static proven in rounds 4-5). 1024 blocks = 4 sequential
//       block-waves/CU -> epilogue C-writes overlap next block's compute
//       (fixes the 1-block/CU serialized write-drain of the 8-phase k3).
//       Octet-XOR conflict-free LDS reads kept (SQ_LDS_BANK_CONFLICT=0, r3).
//       MFMA order tile-by-tile, ks-inner == rounds 4-5 -> bit-identical out.

typedef __attribute__((ext_vector_type(8))) short short8;
typedef __attribute__((ext_vector_type(4))) float floatx4;

#define BM 128
#define BN 128
#define BK 32

#define BATCH 8
#define SEQ 4096
#define DIM 512
#define SPLITK 8

__device__ __forceinline__ void async_copy16(const __hip_bfloat16* g, __hip_bfloat16* l) {
  __builtin_amdgcn_global_load_lds((const __attribute__((address_space(1))) void*)g,
                                   (__attribute__((address_space(3))) void*)l, 16, 0, 0);
}

// Upper-triangle tile map: t in [0,10) -> (ti<=tj) of a 4x4 tile grid.
__device__ __forceinline__ void tri_map(int t, int& ti, int& tj) {
  if (t < 4)      { ti = 0; tj = t; }
  else if (t < 7) { ti = 1; tj = t - 3; }
  else if (t < 9) { ti = 2; tj = t - 5; }
  else            { ti = 3; tj = 3; }
}

// ---------------- k1: transpose+cast (Xt) and swizzled straight cast (Xb16) -
__global__ __launch_bounds__(256) void transpose_cast_kernel(
    const float* __restrict__ X, __hip_bfloat16* __restrict__ Xt,
    __hip_bfloat16* __restrict__ Xb16) {
  __shared__ float tile[64][65];
  const int b = blockIdx.z;
  const int s0 = blockIdx.x * 64;
  const int d0 = blockIdx.y * 64;
  const int tid = threadIdx.x;
  const float* Xb = X + (long)b * SEQ * DIM;
  __hip_bfloat16* Xtb = Xt + (long)b * DIM * SEQ;
  {
    const int c4 = (tid & 15) * 4;
    const int r0 = tid >> 4;  // 0..15
#pragma unroll
    for (int r = 0; r < 64; r += 16) {
      const float4 v = *(const float4*)&Xb[(long)(s0 + r + r0) * DIM + d0 + c4];
      tile[r + r0][c4 + 0] = v.x;
      tile[r + r0][c4 + 1] = v.y;
      tile[r + r0][c4 + 2] = v.z;
      tile[r + r0][c4 + 3] = v.w;
    }
  }
  __syncthreads();
  // Xt[d][s]: pack 8 consecutive s per 16B store.
#pragma unroll
  for (int it = 0; it < 2; ++it) {
    const int idx = it * 256 + tid;    // 0..511
    const int dl = idx >> 3;           // 0..63
    const int so = (idx & 7) * 8;      // 0,8,..,56
    union { short8 v; __hip_bfloat16 e[8]; } u;
#pragma unroll
    for (int j = 0; j < 8; ++j) u.e[j] = __float2bfloat16(tile[so + j][dl]);
    *(short8*)&Xtb[(long)(d0 + dl) * SEQ + s0 + so] = u.v;
  }
  // Xb16[s][d]: straight cast, octet-swizzled within the 64-d block.
  if (Xb16 != nullptr) {
    __hip_bfloat16* Xcb = Xb16 + (long)b * SEQ * DIM;
#pragma unroll
    for (int it = 0; it < 2; ++it) {
      const int idx = it * 256 + tid;  // 0..511
      const int sl = idx >> 3;         // 0..63
      const int dc = idx & 7;          // source 8-wide d chunk
      const int dcs = dc ^ (sl & 7);   // swizzled destination octet
      union { short8 v; __hip_bfloat16 e[8]; } u;
#pragma unroll
      for (int j = 0; j < 8; ++j) u.e[j] = __float2bfloat16(tile[sl][dc * 8 + j]);
      *(short8*)&Xcb[(long)(s0 + sl) * DIM + d0 + dcs * 8] = u.v;
    }
  }
}

// ---------------- GEMM: C = A . Bt^T (2-phase, proven; k2 + k3 fallback) ----
template <int NSPLIT, bool AFP32, int SWZ, typename CT>
__global__ __launch_bounds__(256, 4) void gemm_bt_kernel(
    const float* __restrict__ Af, const __hip_bfloat16* __restrict__ Ab,
    const __hip_bfloat16* __restrict__ Bt, CT* __restrict__ C,
    int K, int lda, int ldb, int ldc, long strideA, long strideB, long strideC) {
  __shared__ __align__(16) __hip_bfloat16 As[2][BM * BK];  // [m][k]
  __shared__ __align__(16) __hip_bfloat16 Bs[2][BN * BK];  // [n][k]

  int bz, m0, n0;
  if constexpr (SWZ == 1) {
    const int lin = blockIdx.x;        // 0..127 per batch
    bz = blockIdx.z;
    const int xcd = lin & 7;
    const int t = lin >> 3;            // 0..15
    n0 = (t & 3) * BN;
    m0 = ((t >> 2) * 8 + xcd) * BM;
  } else if constexpr (SWZ == 2) {
    bz = blockIdx.x;                   // chunk id, fastest dim -> xcd = bz & 7
    int ti, tj;
    tri_map(blockIdx.y, ti, tj);       // upper triangle only
    m0 = ti * BM;
    n0 = tj * BN;
  } else {
    bz = blockIdx.z;
    m0 = blockIdx.y * BM;
    n0 = blockIdx.x * BN;
  }
  const int b = bz / NSPLIT;
  const int split = bz % NSPLIT;
  const int klen = K / NSPLIT;
  const int kb = split * klen;

  const int tid = threadIdx.x;
  const int w = tid >> 6;
  const int lane = tid & 63;
  const int r16 = lane & 15;
  const int kg = lane >> 4;
  const int wr = w >> 1;
  const int wc = w & 1;

  const float* Afb = AFP32 ? Af + b * strideA : nullptr;
  const __hip_bfloat16* Abb = AFP32 ? nullptr : Ab + b * strideA;
  const __hip_bfloat16* Btb = Bt + b * strideB;
  CT* Cb = C + (long)bz * strideC;

  const floatx4 vzero = {0.f, 0.f, 0.f, 0.f};
  floatx4 acc[4][4];
#pragma unroll
  for (int i = 0; i < 4; ++i)
#pragma unroll
    for (int j = 0; j < 4; ++j) acc[i][j] = vzero;

  const int arow = tid >> 1;
  const int ahalf = tid & 1;
  float f[16];

  auto stageB = [&](int buf, int k0) {
#pragma unroll
    for (int q = 0; q < 2; ++q) {
      const __hip_bfloat16* gb =
          Btb + (long)(n0 + w * 32 + q * 16 + (lane >> 2)) * ldb + k0 + (lane & 3) * 8;
      async_copy16(gb, &Bs[buf][(w * 32 + q * 16) * BK]);
    }
  };
  auto stageA = [&](int buf, int k0) {
#pragma unroll
    for (int q = 0; q < 2; ++q) {
      const __hip_bfloat16* ga =
          Abb + (long)(m0 + w * 32 + q * 16 + (lane >> 2)) * lda + k0 + (lane & 3) * 8;
      async_copy16(ga, &As[buf][(w * 32 + q * 16) * BK]);
    }
  };
  auto loadF = [&](int k0) {
    const float* ar = Afb + (long)(m0 + arow) * lda + k0 + ahalf * 16;
    *(float4*)(f + 0)  = *(const float4*)(ar + 0);
    *(float4*)(f + 4)  = *(const float4*)(ar + 4);
    *(float4*)(f + 8)  = *(const float4*)(ar + 8);
    *(float4*)(f + 12) = *(const float4*)(ar + 12);
  };
  auto writeF = [&](int buf) {
    union { short8 v[2]; __hip_bfloat16 e[16]; } u;
#pragma unroll
    for (int t = 0; t < 16; ++t) u.e[t] = __float2bfloat16(f[t]);
    short8* dst = (short8*)&As[buf][arow * BK + ahalf * 16];
    dst[0] = u.v[0];
    dst[1] = u.v[1];
  };

  const int nIter = klen / BK;
  if constexpr (AFP32) {
    loadF(kb);
    writeF(0);
    loadF(kb + BK);
  } else {
    stageA(0, kb);
  }
  stageB(0, kb);

  for (int t = 0; t < nIter; ++t) {
    const int cur = t & 1;
    __syncthreads();
    if (t + 1 < nIter) {
      if constexpr (AFP32) {
        writeF(cur ^ 1);
        if (t + 2 < nIter) loadF(kb + (t + 2) * BK);
      } else {
        stageA(cur ^ 1, kb + (t + 1) * BK);
      }
      stageB(cur ^ 1, kb + (t + 1) * BK);
    }

    short8 a[4], bfrag[4];
#pragma unroll
    for (int i = 0; i < 4; ++i)
      a[i] = *(const short8*)&As[cur][(wr * 64 + i * 16 + r16) * BK + kg * 8];
#pragma unroll
    for (int j = 0; j < 4; ++j)
      bfrag[j] = *(const short8*)&Bs[cur][(wc * 64 + j * 16 + r16) * BK + kg * 8];
#pragma unroll
    for (int i = 0; i < 4; ++i)
#pragma unroll
      for (int j = 0; j < 4; ++j)
        acc[i][j] = __builtin_amdgcn_mfma_f32_16x16x32_bf16(a[i], bfrag[j], acc[i][j], 0, 0, 0);
  }

#pragma unroll
  for (int i = 0; i < 4; ++i) {
    const int row_base = m0 + wr * 64 + i * 16 + kg * 4;
#pragma unroll
    for (int j = 0; j < 4; ++j) {
      const int col = n0 + wc * 64 + j * 16 + r16;
#pragma unroll
      for (int r = 0; r < 4; ++r) {
        const float v = acc[i][j][r];
        if constexpr (std::is_same<CT, float>::value)
          Cb[(long)(row_base + r) * ldc + col] = v;
        else
          Cb[(long)(row_base + r) * ldc + col] = __float2bfloat16(v);
      }
    }
  }
}

// ---------------- k3: B-panel-resident GEMM, out = Xb16 . gram^T ------------
// 512 thr (8 waves, 2M x 4N: wave tile 64x32). Tile 128x128, K=512.
// LDS: Bp[128][512] (whole gram panel, 128KB) + A[2][128][64] (32KB) = 160KB.
// K-loop ledger (NT=8 tiles of K64, A single-dbuf, stage t+2 into buf[t&1]):
//   prologue: stgB(16 loads) + stgA(buf0,T0)(2) + stgA(buf1,T1)(2) = 20
//             outstanding; vmcnt(2) waits oldest 18 (B+A0); barrier.
//   tile t:   ds_read 12 frags (A buf[t&1] + Bp); lgkmcnt(0); barrier
//             [all waves done reading buf[t&1]]; if t<6 stgA(buf[t&1], T(t+2));
//             MFMA x16 (setprio); gate: t<6 vmcnt(2) [waits T(t+1), leaves
//             T(t+2) in flight], t==6 vmcnt(0) [tail: T7 must land], t==7
//             none; barrier (skip at t==7).
// Reads use the octet-XOR baked into global content (k1's Xb16: oct^=s&7;
// kr's gram: oct^=row&7) -> 16 r16-lanes spread over 8 bank phases (2-way,
// free; SQ_LDS_BANK_CONFLICT=0 measured round 3). MFMA order: tiles 0..7,
// ks inner 0,1 == rounds 4-5 -> bit-identical output.
#define VMCNT2() asm volatile("s_waitcnt vmcnt(2)" ::: "memory")
#define VMCNT0() asm volatile("s_waitcnt vmcnt(0)" ::: "memory")
#define BAR() asm volatile("s_barrier" ::: "memory")
#define LGKM0()                                            \
  do {                                                     \
    asm volatile("s_waitcnt lgkmcnt(0)" ::: "memory");     \
    __builtin_amdgcn_sched_barrier(0);                     \
  } while (0)

__global__ __launch_bounds__(512, 2) void gemm_bres_kernel(
    const __hip_bfloat16* __restrict__ Xs,  // swizzled Xb16 [B][S][D]
    const __hip_bfloat16* __restrict__ G,   // swizzled gram [B][D][D]
    float* __restrict__ C) {
  __shared__ __align__(16) __hip_bfloat16 smem[81920];  // 160KB exactly
  __hip_bfloat16* Bp = smem;            // [128][512]
  __hip_bfloat16* Ab = smem + 65536;    // [2][128][64]

  const int bid = blockIdx.x;      // 1024 blocks
  const int b  = bid & 7;          // batch b -> XCD b (gram+Xb16 L2-resident)
  const int t  = bid >> 3;         // 0..127
  const int m0 = (t >> 2) * BM;    // consecutive bids share m0 -> L2 reuse
  const int n0 = (t & 3) * BN;

  const int tid = threadIdx.x;
  const int w = tid >> 6;          // 0..7
  const int lane = tid & 63;
  const int r16 = lane & 15;
  const int kg = lane >> 4;
  const int wm = w >> 2;           // 0..1 (M: 64 rows)
  const int wn = w & 3;            // 0..3 (N: 32 cols)
  const int ph = r16 & 7;

  const __hip_bfloat16* Xb = Xs + (long)b * SEQ * DIM;
  const __hip_bfloat16* Gb = G + (long)b * DIM * DIM;
  float* Cb = C + (long)b * SEQ * DIM;

  // A K-tile kt -> buf d: 128 rows x 64 cols = 16KB = 2 passes x 512 thr x 16B.
  auto stgA = [&](int d, int kt) {
#pragma unroll
    for (int R = 0; R < 2; ++R) {
      const int rt = R * 64 + w * 8;  // wave-uniform row base; lane>>3 = row
      const __hip_bfloat16* g =
          Xb + (long)(m0 + rt + (lane >> 3)) * DIM + kt * 64 + (lane & 7) * 8;
      async_copy16(g, &Ab[d * 8192 + rt * 64]);
    }
  };

  // Prologue: whole B-panel (rows n0..n0+128 of gram, linear copy) + A0, A1.
  {
#pragma unroll
    for (int p = 0; p < 16; ++p) {
      const int e0 = (p * 8 + w) * 512;  // wave-uniform elem base; lane*8 offs
      async_copy16(Gb + (long)n0 * DIM + e0 + lane * 8, &Bp[e0]);
    }
  }
  stgA(0, 0);
  stgA(1, 1);
  VMCNT2();  // oldest 18 = B-panel + A0 landed; A1 stays in flight
  BAR();

  const floatx4 vzero = {0.f, 0.f, 0.f, 0.f};
  floatx4 acc[4][2];
#pragma unroll
  for (int i = 0; i < 4; ++i)
#pragma unroll
    for (int j = 0; j < 2; ++j) acc[i][j] = vzero;

  const int NT = DIM / 64;  // 8
#pragma unroll
  for (int tk = 0; tk < NT; ++tk) {
    const int cur = tk & 1;
    short8 af[4][2], bf[2][2];
#pragma unroll
    for (int mi = 0; mi < 4; ++mi)
#pragma unroll
      for (int ks = 0; ks < 2; ++ks)
        af[mi][ks] = *(const short8*)&Ab[cur * 8192 +
            (wm * 64 + mi * 16 + r16) * 64 + (((ks * 4 + kg) ^ ph) * 8)];
#pragma unroll
    for (int nj = 0; nj < 2; ++nj)
#pragma unroll
      for (int ks = 0; ks < 2; ++ks)
        bf[nj][ks] = *(const short8*)&Bp[
            (wn * 32 + nj * 16 + r16) * 512 + tk * 64 + (((ks * 4 + kg) ^ ph) * 8)];
    LGKM0();   // frags in regs: safe to overwrite buf[cur] after the barrier
    BAR();
    if (tk + 2 < NT) stgA(cur, tk + 2);
    __builtin_amdgcn_s_setprio(1);
#pragma unroll
    for (int mi = 0; mi < 4; ++mi)
#pragma unroll
      for (int nj = 0; nj < 2; ++nj)
#pragma unroll
        for (int ks = 0; ks < 2; ++ks)
          acc[mi][nj] = __builtin_amdgcn_mfma_f32_16x16x32_bf16(
              af[mi][ks], bf[nj][ks], acc[mi][nj], 0, 0, 0);
    __builtin_amdgcn_s_setprio(0);
    __builtin_amdgcn_sched_barrier(0);
    if (tk < NT - 2) {
      VMCNT2();  // T(tk+1) landed; T(tk+2) stays in flight
      BAR();
    } else if (tk == NT - 2) {
      VMCNT0();  // tail: T7 must land
      BAR();
    }               // tk == NT-1: no gate, fall through to epilogue
  }

  // Epilogue: row = kg*4 + r, col = r16 (m89-verified C/D map)
#pragma unroll
  for (int mi = 0; mi < 4; ++mi) {
    const int row_base = m0 + wm * 64 + mi * 16 + kg * 4;
#pragma unroll
    for (int nj = 0; nj < 2; ++nj) {
      const int col = n0 + wn * 32 + nj * 16 + r16;
#pragma unroll
      for (int r = 0; r < 4; ++r)
        Cb[(long)(row_base + r) * DIM + col] = acc[mi][nj][r];
    }
  }
}

// ---------------- kr: reduce NSPLIT partials (triangle) -> full gram --------
// SWZG: store gram with octet-XOR (oct ^= row&7 per 64-col window) for k3;
// plain layout for the fallback path.
template <int NSPLIT, bool SWZG>
__global__ __launch_bounds__(256) void reduce_mirror_kernel(
    const __hip_bfloat16* __restrict__ P, __hip_bfloat16* __restrict__ G) {
  __shared__ float tile[64][65];
  int ti, tj;
  tri_map(blockIdx.x, ti, tj);
  const int b = blockIdx.y;
  const __hip_bfloat16* Pb = P + (long)b * NSPLIT * DIM * DIM;
  __hip_bfloat16* Gb = G + (long)b * DIM * DIM;
  const int r0 = ti * 128, c0 = tj * 128;
  const int tid = threadIdx.x;
  const int lrow = tid >> 3;        // 0..31
  const int lcol = (tid & 7) * 8;   // 0..56
  const int soct = SWZG ? (((tid & 7) ^ (lrow & 7)) * 8) : lcol;

#pragma unroll
  for (int q = 0; q < 4; ++q) {
    const int qr = (q >> 1) * 64, qc = (q & 1) * 64;
    float s[2][8];
#pragma unroll
    for (int h = 0; h < 2; ++h) {
      const int row = lrow + h * 32;
#pragma unroll
      for (int j = 0; j < 8; ++j) s[h][j] = 0.f;
#pragma unroll
      for (int p = 0; p < NSPLIT; ++p) {
        union { short8 v; __hip_bfloat16 e8[8]; } u;
        u.v = *(const short8*)&Pb[(long)p * DIM * DIM +
                                  (long)(r0 + qr + row) * DIM + c0 + qc + lcol];
#pragma unroll
        for (int j = 0; j < 8; ++j) s[h][j] += __bfloat162float(u.e8[j]);
      }
      union { short8 v; __hip_bfloat16 e8[8]; } o;
#pragma unroll
      for (int j = 0; j < 8; ++j) o.e8[j] = __float2bfloat16(s[h][j]);
      // (row&7) == (lrow&7): r0,qr,h*32 all = 0 mod 8
      *(short8*)&Gb[(long)(r0 + qr + row) * DIM + c0 + qc + soct] = o.v;
    }
    if (ti != tj) {
      if (q) __syncthreads();
#pragma unroll
      for (int h = 0; h < 2; ++h) {
        const int row = lrow + h * 32;
#pragma unroll
        for (int j = 0; j < 8; ++j) tile[row][lcol + j] = s[h][j];
      }
      __syncthreads();
#pragma unroll
      for (int it = 0; it < 2; ++it) {
        const int idx = it * 256 + tid;
        const int dl = idx >> 3;          // mirror row offset (0..63)
        const int so = (idx & 7) * 8;     // mirror col chunk
        const int soct2 = SWZG ? (((idx & 7) ^ (dl & 7)) * 8) : so;
        union { short8 v; __hip_bfloat16 e8[8]; } o;
#pragma unroll
        for (int j = 0; j < 8; ++j) o.e8[j] = __float2bfloat16(tile[so + j][dl]);
        *(short8*)&Gb[(long)(c0 + qc + dl) * DIM + r0 + qr + soct2] = o.v;
      }
    }
  }
}

// ---------------- host launch ----------------------------------------------
extern "C" void kernel_launch(void* const* d_in, const int* in_sizes, int n_in,
                              void* d_out, int out_size, void* d_ws, size_t ws_size,
                              hipStream_t stream) {
  const float* X = (const float*)d_in[0];
  float* out = (float*)d_out;
  const long xtBytes = (long)BATCH * DIM * SEQ * 2;               // 33.5 MB
  const long gramBytes = (long)BATCH * DIM * DIM * 2;             // 4.2 MB
  const long partBytes = (long)BATCH * SPLITK * DIM * DIM * 2;    // 33.5 MB (bf16)
  __hip_bfloat16* Xt = (__hip_bfloat16*)d_out;
  __hip_bfloat16* gram = (__hip_bfloat16*)d_ws;

  const bool bigWs = ws_size >= (size_t)(gramBytes + xtBytes + partBytes);
  const bool midWs = ws_size >= (size_t)(gramBytes + xtBytes);
  __hip_bfloat16* Xb16 = midWs ? (__hip_bfloat16*)((char*)d_ws + gramBytes) : nullptr;

  // k1: Xt[b][d][s] (+ swizzled Xb16[b][s][d] if ws fits)
  transpose_cast_kernel<<<dim3(SEQ / 64, DIM / 64, BATCH), 256, 0, stream>>>(X, Xt, Xb16);

  // k2: split-8 gram partials (bf16), upper-triangle tiles only (symmetry)
  __hip_bfloat16* partials = bigWs
      ? (__hip_bfloat16*)((char*)d_ws + gramBytes + xtBytes)
      : (__hip_bfloat16*)((char*)d_out + xtBytes);
  gemm_bt_kernel<SPLITK, false, 2, __hip_bfloat16>
      <<<dim3(BATCH * SPLITK, 10, 1), 256, 0, stream>>>(
          nullptr, Xt, Xt, partials, SEQ, SEQ, SEQ, DIM,
          (long)DIM * SEQ, (long)DIM * SEQ, (long)DIM * DIM);

  // kr: triangle partials -> full gram (mirror off-diagonal tiles)
  if (midWs) {
    reduce_mirror_kernel<SPLITK, true><<<dim3(10, BATCH), 256, 0, stream>>>(
        partials, gram);
    // k3: B-panel-resident, 1024 blocks (4 block-waves/CU, epilogue overlap)
    gemm_bres_kernel<<<dim3(1024, 1, 1), 512, 0, stream>>>(Xb16, gram, out);
  } else {
    reduce_mirror_kernel<SPLITK, false><<<dim3(10, BATCH), 256, 0, stream>>>(
        partials, gram);
    gemm_bt_kernel<1, true, 1, float><<<dim3(128, 1, BATCH), 256, 0, stream>>>(
        X, nullptr, gram, out, DIM, DIM, DIM, DIM,
        (long)SEQ * DIM, (long)DIM * DIM, (long)SEQ * DIM);
  }
}

// Round 7
// 162.176 us; speedup vs baseline: 1.0389x; 1.0389x over previous
//
#include <hip/hip_runtime.h>
#include <hip/hip_bf16.h>
#include <type_traits>

// out[b] = X[b] @ (X[b]^T @ X[b]);  B=8, S=4096, D=512, fp32 in/out.
// Pipeline (bf16 MFMA, fp32 accumulate), ws = 268MB observed:
//   k1: Xt[d][s] bf16 -> d_out[0:33.5M) ; Xb16[s][d] bf16 (octet-swizzled
//       per 64-d window: oct ^= s&7) -> ws+4.2M
//   k2: split-K=8 gram partials bf16, upper-triangle tiles only (symmetry),
//       XCD-swizzled, LDS dbuf (proven 2-phase gemm_bt) -> ws+37.7M
//   kr: reduce 8 bf16 partials -> full bf16 gram via LDS-transpose mirror;
//       gram stored octet-swizzled (oct ^= row&7 per 64-col window) for k3.
//   k3: 8-phase 256^2 deep-pipelined GEMM (T3+T4 counted vmcnt, T5 setprio,
//       phase-boundary pinning). Round-7 NOTE: this is the measured-best k3
//       (29.5us). Round-6's B-panel-resident variant (160KB LDS) regressed
//       to 35.5us: zero co-residency means block-wave i+1 waits for block i
//       to release LDS, exposing 4x {B-panel prologue + fill/drain}; the
//       epilogue-overlap premise requires co-resident blocks (<=80KB LDS),
//       infeasible for any 256^2 double-buffered schedule.

typedef __attribute__((ext_vector_type(8))) short short8;
typedef __attribute__((ext_vector_type(4))) float floatx4;

#define BM 128
#define BN 128
#define BK 32

#define BATCH 8
#define SEQ 4096
#define DIM 512
#define SPLITK 8

__device__ __forceinline__ void async_copy16(const __hip_bfloat16* g, __hip_bfloat16* l) {
  __builtin_amdgcn_global_load_lds((const __attribute__((address_space(1))) void*)g,
                                   (__attribute__((address_space(3))) void*)l, 16, 0, 0);
}

// Upper-triangle tile map: t in [0,10) -> (ti<=tj) of a 4x4 tile grid.
__device__ __forceinline__ void tri_map(int t, int& ti, int& tj) {
  if (t < 4)      { ti = 0; tj = t; }
  else if (t < 7) { ti = 1; tj = t - 3; }
  else if (t < 9) { ti = 2; tj = t - 5; }
  else            { ti = 3; tj = 3; }
}

// ---------------- k1: transpose+cast (Xt) and swizzled straight cast (Xb16) -
__global__ __launch_bounds__(256) void transpose_cast_kernel(
    const float* __restrict__ X, __hip_bfloat16* __restrict__ Xt,
    __hip_bfloat16* __restrict__ Xb16) {
  __shared__ float tile[64][65];
  const int b = blockIdx.z;
  const int s0 = blockIdx.x * 64;
  const int d0 = blockIdx.y * 64;
  const int tid = threadIdx.x;
  const float* Xb = X + (long)b * SEQ * DIM;
  __hip_bfloat16* Xtb = Xt + (long)b * DIM * SEQ;
  {
    const int c4 = (tid & 15) * 4;
    const int r0 = tid >> 4;  // 0..15
#pragma unroll
    for (int r = 0; r < 64; r += 16) {
      const float4 v = *(const float4*)&Xb[(long)(s0 + r + r0) * DIM + d0 + c4];
      tile[r + r0][c4 + 0] = v.x;
      tile[r + r0][c4 + 1] = v.y;
      tile[r + r0][c4 + 2] = v.z;
      tile[r + r0][c4 + 3] = v.w;
    }
  }
  __syncthreads();
  // Xt[d][s]: pack 8 consecutive s per 16B store.
#pragma unroll
  for (int it = 0; it < 2; ++it) {
    const int idx = it * 256 + tid;    // 0..511
    const int dl = idx >> 3;           // 0..63
    const int so = (idx & 7) * 8;      // 0,8,..,56
    union { short8 v; __hip_bfloat16 e[8]; } u;
#pragma unroll
    for (int j = 0; j < 8; ++j) u.e[j] = __float2bfloat16(tile[so + j][dl]);
    *(short8*)&Xtb[(long)(d0 + dl) * SEQ + s0 + so] = u.v;
  }
  // Xb16[s][d]: straight cast, octet-swizzled within the 64-d block.
  if (Xb16 != nullptr) {
    __hip_bfloat16* Xcb = Xb16 + (long)b * SEQ * DIM;
#pragma unroll
    for (int it = 0; it < 2; ++it) {
      const int idx = it * 256 + tid;  // 0..511
      const int sl = idx >> 3;         // 0..63
      const int dc = idx & 7;          // source 8-wide d chunk
      const int dcs = dc ^ (sl & 7);   // swizzled destination octet
      union { short8 v; __hip_bfloat16 e[8]; } u;
#pragma unroll
      for (int j = 0; j < 8; ++j) u.e[j] = __float2bfloat16(tile[sl][dc * 8 + j]);
      *(short8*)&Xcb[(long)(s0 + sl) * DIM + d0 + dcs * 8] = u.v;
    }
  }
}

// ---------------- GEMM: C = A . Bt^T (2-phase, proven; k2 + k3 fallback) ----
template <int NSPLIT, bool AFP32, int SWZ, typename CT>
__global__ __launch_bounds__(256, 4) void gemm_bt_kernel(
    const float* __restrict__ Af, const __hip_bfloat16* __restrict__ Ab,
    const __hip_bfloat16* __restrict__ Bt, CT* __restrict__ C,
    int K, int lda, int ldb, int ldc, long strideA, long strideB, long strideC) {
  __shared__ __align__(16) __hip_bfloat16 As[2][BM * BK];  // [m][k]
  __shared__ __align__(16) __hip_bfloat16 Bs[2][BN * BK];  // [n][k]

  int bz, m0, n0;
  if constexpr (SWZ == 1) {
    const int lin = blockIdx.x;        // 0..127 per batch
    bz = blockIdx.z;
    const int xcd = lin & 7;
    const int t = lin >> 3;            // 0..15
    n0 = (t & 3) * BN;
    m0 = ((t >> 2) * 8 + xcd) * BM;
  } else if constexpr (SWZ == 2) {
    bz = blockIdx.x;                   // chunk id, fastest dim -> xcd = bz & 7
    int ti, tj;
    tri_map(blockIdx.y, ti, tj);       // upper triangle only
    m0 = ti * BM;
    n0 = tj * BN;
  } else {
    bz = blockIdx.z;
    m0 = blockIdx.y * BM;
    n0 = blockIdx.x * BN;
  }
  const int b = bz / NSPLIT;
  const int split = bz % NSPLIT;
  const int klen = K / NSPLIT;
  const int kb = split * klen;

  const int tid = threadIdx.x;
  const int w = tid >> 6;
  const int lane = tid & 63;
  const int r16 = lane & 15;
  const int kg = lane >> 4;
  const int wr = w >> 1;
  const int wc = w & 1;

  const float* Afb = AFP32 ? Af + b * strideA : nullptr;
  const __hip_bfloat16* Abb = AFP32 ? nullptr : Ab + b * strideA;
  const __hip_bfloat16* Btb = Bt + b * strideB;
  CT* Cb = C + (long)bz * strideC;

  const floatx4 vzero = {0.f, 0.f, 0.f, 0.f};
  floatx4 acc[4][4];
#pragma unroll
  for (int i = 0; i < 4; ++i)
#pragma unroll
    for (int j = 0; j < 4; ++j) acc[i][j] = vzero;

  const int arow = tid >> 1;
  const int ahalf = tid & 1;
  float f[16];

  auto stageB = [&](int buf, int k0) {
#pragma unroll
    for (int q = 0; q < 2; ++q) {
      const __hip_bfloat16* gb =
          Btb + (long)(n0 + w * 32 + q * 16 + (lane >> 2)) * ldb + k0 + (lane & 3) * 8;
      async_copy16(gb, &Bs[buf][(w * 32 + q * 16) * BK]);
    }
  };
  auto stageA = [&](int buf, int k0) {
#pragma unroll
    for (int q = 0; q < 2; ++q) {
      const __hip_bfloat16* ga =
          Abb + (long)(m0 + w * 32 + q * 16 + (lane >> 2)) * lda + k0 + (lane & 3) * 8;
      async_copy16(ga, &As[buf][(w * 32 + q * 16) * BK]);
    }
  };
  auto loadF = [&](int k0) {
    const float* ar = Afb + (long)(m0 + arow) * lda + k0 + ahalf * 16;
    *(float4*)(f + 0)  = *(const float4*)(ar + 0);
    *(float4*)(f + 4)  = *(const float4*)(ar + 4);
    *(float4*)(f + 8)  = *(const float4*)(ar + 8);
    *(float4*)(f + 12) = *(const float4*)(ar + 12);
  };
  auto writeF = [&](int buf) {
    union { short8 v[2]; __hip_bfloat16 e[16]; } u;
#pragma unroll
    for (int t = 0; t < 16; ++t) u.e[t] = __float2bfloat16(f[t]);
    short8* dst = (short8*)&As[buf][arow * BK + ahalf * 16];
    dst[0] = u.v[0];
    dst[1] = u.v[1];
  };

  const int nIter = klen / BK;
  if constexpr (AFP32) {
    loadF(kb);
    writeF(0);
    loadF(kb + BK);
  } else {
    stageA(0, kb);
  }
  stageB(0, kb);

  for (int t = 0; t < nIter; ++t) {
    const int cur = t & 1;
    __syncthreads();
    if (t + 1 < nIter) {
      if constexpr (AFP32) {
        writeF(cur ^ 1);
        if (t + 2 < nIter) loadF(kb + (t + 2) * BK);
      } else {
        stageA(cur ^ 1, kb + (t + 1) * BK);
      }
      stageB(cur ^ 1, kb + (t + 1) * BK);
    }

    short8 a[4], bfrag[4];
#pragma unroll
    for (int i = 0; i < 4; ++i)
      a[i] = *(const short8*)&As[cur][(wr * 64 + i * 16 + r16) * BK + kg * 8];
#pragma unroll
    for (int j = 0; j < 4; ++j)
      bfrag[j] = *(const short8*)&Bs[cur][(wc * 64 + j * 16 + r16) * BK + kg * 8];
#pragma unroll
    for (int i = 0; i < 4; ++i)
#pragma unroll
      for (int j = 0; j < 4; ++j)
        acc[i][j] = __builtin_amdgcn_mfma_f32_16x16x32_bf16(a[i], bfrag[j], acc[i][j], 0, 0, 0);
  }

#pragma unroll
  for (int i = 0; i < 4; ++i) {
    const int row_base = m0 + wr * 64 + i * 16 + kg * 4;
#pragma unroll
    for (int j = 0; j < 4; ++j) {
      const int col = n0 + wc * 64 + j * 16 + r16;
#pragma unroll
      for (int r = 0; r < 4; ++r) {
        const float v = acc[i][j][r];
        if constexpr (std::is_same<CT, float>::value)
          Cb[(long)(row_base + r) * ldc + col] = v;
        else
          Cb[(long)(row_base + r) * ldc + col] = __float2bfloat16(v);
      }
    }
  }
}

// ---------------- k3: 8-phase 256x256 GEMM, out = Xb16 . gram^T -------------
// Schedule ledger (NT=8 K-tiles of 64; iter J computes tiles 2J (buf0) and
// 2J+1 (buf1); one half-tile (2 gload_lds/thread) staged per phase):
//   ph1: T(2J+1).A0  ph2: T(2J+1).A1  ph3: T(2J+2).B0  ph4: T(2J+2).B1
//   ph5: T(2J+2).A0  ph6: T(2J+2).A1  ph7: T(2J+3).B0  ph8: T(2J+3).B1
// vmcnt gates at ph4/ph8 only (counted, never 0 mid-loop): outstanding = 12,
// oldest 8 must land -> vmcnt(4). Last iter: ph4 gates vmcnt(0), ph8 none.
// Phase pinning: opening s_barrier -> s_waitcnt lgkmcnt(0) -> sched_barrier(0)
// -> setprio(1) MFMA setprio(0) -> sched_barrier(0) -> [gate] -> s_barrier.
// LDS reads conflict-free via octet-XOR baked into global content (k1/kr),
// round-3 measured SQ_LDS_BANK_CONFLICT = 0.
#define VMCNT4() asm volatile("s_waitcnt vmcnt(4)" ::: "memory")
#define VMCNT0() asm volatile("s_waitcnt vmcnt(0)" ::: "memory")
#define BAR() asm volatile("s_barrier" ::: "memory")
#define OPEN_PIN()                                         \
  do {                                                     \
    asm volatile("s_waitcnt lgkmcnt(0)" ::: "memory");     \
    __builtin_amdgcn_sched_barrier(0);                     \
  } while (0)
#define CLOSE_PIN() __builtin_amdgcn_sched_barrier(0)

__global__ __launch_bounds__(512, 2) void gemm_8ph_kernel(
    const __hip_bfloat16* __restrict__ Xs,  // swizzled Xb16 [B][S][D]
    const __hip_bfloat16* __restrict__ G,   // swizzled gram [B][D][D]
    float* __restrict__ C) {
  // A: [2][256][64] at 0, B: [2][256][64] at +32768 elems (128KB total)
  __shared__ __align__(16) __hip_bfloat16 smem[65536];
  __hip_bfloat16* Asm = smem;
  __hip_bfloat16* Bsm = smem + 32768;

  const int b  = blockIdx.x & 7;   // one batch per XCD (32 tiles = 32 CUs)
  const int tt = blockIdx.x >> 3;  // 0..31
  const int m0 = (tt >> 1) * 256;
  const int n0 = (tt & 1) * 256;

  const int tid = threadIdx.x;
  const int w = tid >> 6;          // 0..7
  const int lane = tid & 63;
  const int r16 = lane & 15;
  const int kg = lane >> 4;
  const int wm = w >> 2;           // 0..1 (M)
  const int wn = w & 3;            // 0..3 (N)
  const int ph = r16 & 7;

  const __hip_bfloat16* Xb = Xs + (long)b * SEQ * DIM;
  const __hip_bfloat16* Gb = G + (long)b * DIM * DIM;
  float* Cb = C + (long)b * SEQ * DIM;

  // half h (rows h*128..+128) of K-tile kt -> buf d. 2 rounds x 8KB.
  auto stgA = [&](int d, int h, int kt) {
#pragma unroll
    for (int R = 0; R < 2; ++R) {
      const int rt = h * 128 + R * 64 + w * 8;  // wave-uniform row base
      const __hip_bfloat16* g =
          Xb + (long)(m0 + rt + (lane >> 3)) * DIM + kt * 64 + (lane & 7) * 8;
      async_copy16(g, &Asm[d * 16384 + rt * 64]);
    }
  };
  auto stgB = [&](int d, int h, int kt) {
#pragma unroll
    for (int R = 0; R < 2; ++R) {
      const int rt = h * 128 + R * 64 + w * 8;
      const __hip_bfloat16* g =
          Gb + (long)(n0 + rt + (lane >> 3)) * DIM + kt * 64 + (lane & 7) * 8;
      async_copy16(g, &Bsm[d * 16384 + rt * 64]);
    }
  };

  const floatx4 vzero = {0.f, 0.f, 0.f, 0.f};
  floatx4 acc[8][4];
#pragma unroll
  for (int i = 0; i < 8; ++i)
#pragma unroll
    for (int j = 0; j < 4; ++j) acc[i][j] = vzero;

  short8 af[2][2], bf[4][2];

#define LDA8(q, d)                                                              \
  {                                                                             \
    _Pragma("unroll") for (int m2 = 0; m2 < 2; ++m2)                            \
    _Pragma("unroll") for (int ks = 0; ks < 2; ++ks)                            \
      af[m2][ks] = *(const short8*)&Asm[(d) * 16384 +                           \
          (wm * 128 + ((q) * 2 + m2) * 16 + r16) * 64 + (((ks * 4 + kg) ^ ph) * 8)]; \
  }
#define LDB8(d)                                                                 \
  {                                                                             \
    _Pragma("unroll") for (int nj = 0; nj < 4; ++nj)                            \
    _Pragma("unroll") for (int ks = 0; ks < 2; ++ks)                            \
      bf[nj][ks] = *(const short8*)&Bsm[(d) * 16384 +                           \
          (wn * 64 + nj * 16 + r16) * 64 + (((ks * 4 + kg) ^ ph) * 8)];         \
  }
#define MFMAQ(q)                                                                \
  {                                                                             \
    __builtin_amdgcn_s_setprio(1);                                              \
    _Pragma("unroll") for (int m2 = 0; m2 < 2; ++m2)                            \
    _Pragma("unroll") for (int nj = 0; nj < 4; ++nj)                            \
    _Pragma("unroll") for (int ks = 0; ks < 2; ++ks)                            \
      acc[(q) * 2 + m2][nj] = __builtin_amdgcn_mfma_f32_16x16x32_bf16(          \
          af[m2][ks], bf[nj][ks], acc[(q) * 2 + m2][nj], 0, 0, 0);              \
    __builtin_amdgcn_s_setprio(0);                                              \
  }

  // Prologue: T0 fully (B then A) + T1.B -> 12 loads; wait oldest 8 (=T0).
  stgB(0, 0, 0); stgB(0, 1, 0);
  stgA(0, 0, 0); stgA(0, 1, 0);
  stgB(1, 0, 1); stgB(1, 1, 1);
  VMCNT4();
  BAR();

  const int NI = DIM / 128;  // 4 iterations, 2 K-tiles each
#pragma unroll
  for (int J = 0; J < NI; ++J) {
    const int t0 = 2 * J;
    const bool g2 = (t0 + 2) < 8;   // stage tile t0+2? (constant after unroll)
    const bool g3 = (t0 + 3) < 8;   // stage tile t0+3?
    // ---- K-tile t0 (buf0) ----
    LDB8(0); LDA8(0, 0);
    stgA(1, 0, t0 + 1);
    BAR(); OPEN_PIN(); MFMAQ(0); CLOSE_PIN(); BAR();

    LDA8(1, 0);
    stgA(1, 1, t0 + 1);
    BAR(); OPEN_PIN(); MFMAQ(1); CLOSE_PIN(); BAR();

    LDA8(2, 0);
    if (g2) stgB(0, 0, t0 + 2);
    BAR(); OPEN_PIN(); MFMAQ(2); CLOSE_PIN(); BAR();

    LDA8(3, 0);
    if (g2) stgB(0, 1, t0 + 2);
    BAR(); OPEN_PIN(); MFMAQ(3); CLOSE_PIN();
    if (J < NI - 1) { VMCNT4(); } else { VMCNT0(); }
    BAR();
    // ---- K-tile t0+1 (buf1) ----
    LDB8(1); LDA8(0, 1);
    if (g2) stgA(0, 0, t0 + 2);
    BAR(); OPEN_PIN(); MFMAQ(0); CLOSE_PIN(); BAR();

    LDA8(1, 1);
    if (g2) stgA(0, 1, t0 + 2);
    BAR(); OPEN_PIN(); MFMAQ(1); CLOSE_PIN(); BAR();

    LDA8(2, 1);
    if (g3) stgB(1, 0, t0 + 3);
    BAR(); OPEN_PIN(); MFMAQ(2); CLOSE_PIN(); BAR();

    LDA8(3, 1);
    if (g3) stgB(1, 1, t0 + 3);
    BAR(); OPEN_PIN(); MFMAQ(3); CLOSE_PIN();
    if (J < NI - 1) { VMCNT4(); BAR(); }
  }

  // Epilogue: row = kg*4 + r, col = r16 (m89-verified C/D map)
#pragma unroll
  for (int mi = 0; mi < 8; ++mi) {
    const int row_base = m0 + wm * 128 + mi * 16 + kg * 4;
#pragma unroll
    for (int nj = 0; nj < 4; ++nj) {
      const int col = n0 + wn * 64 + nj * 16 + r16;
#pragma unroll
      for (int r = 0; r < 4; ++r)
        Cb[(long)(row_base + r) * DIM + col] = acc[mi][nj][r];
    }
  }
#undef LDA8
#undef LDB8
#undef MFMAQ
}

// ---------------- kr: reduce NSPLIT partials (triangle) -> full gram --------
// SWZG: store gram with octet-XOR (oct ^= row&7 per 64-col window) for the
// 8-phase k3; plain layout for the fallback path.
template <int NSPLIT, bool SWZG>
__global__ __launch_bounds__(256) void reduce_mirror_kernel(
    const __hip_bfloat16* __restrict__ P, __hip_bfloat16* __restrict__ G) {
  __shared__ float tile[64][65];
  int ti, tj;
  tri_map(blockIdx.x, ti, tj);
  const int b = blockIdx.y;
  const __hip_bfloat16* Pb = P + (long)b * NSPLIT * DIM * DIM;
  __hip_bfloat16* Gb = G + (long)b * DIM * DIM;
  const int r0 = ti * 128, c0 = tj * 128;
  const int tid = threadIdx.x;
  const int lrow = tid >> 3;        // 0..31
  const int lcol = (tid & 7) * 8;   // 0..56
  const int soct = SWZG ? (((tid & 7) ^ (lrow & 7)) * 8) : lcol;

#pragma unroll
  for (int q = 0; q < 4; ++q) {
    const int qr = (q >> 1) * 64, qc = (q & 1) * 64;
    float s[2][8];
#pragma unroll
    for (int h = 0; h < 2; ++h) {
      const int row = lrow + h * 32;
#pragma unroll
      for (int j = 0; j < 8; ++j) s[h][j] = 0.f;
#pragma unroll
      for (int p = 0; p < NSPLIT; ++p) {
        union { short8 v; __hip_bfloat16 e8[8]; } u;
        u.v = *(const short8*)&Pb[(long)p * DIM * DIM +
                                  (long)(r0 + qr + row) * DIM + c0 + qc + lcol];
#pragma unroll
        for (int j = 0; j < 8; ++j) s[h][j] += __bfloat162float(u.e8[j]);
      }
      union { short8 v; __hip_bfloat16 e8[8]; } o;
#pragma unroll
      for (int j = 0; j < 8; ++j) o.e8[j] = __float2bfloat16(s[h][j]);
      // (row&7) == (lrow&7): r0,qr,h*32 all = 0 mod 8
      *(short8*)&Gb[(long)(r0 + qr + row) * DIM + c0 + qc + soct] = o.v;
    }
    if (ti != tj) {
      if (q) __syncthreads();
#pragma unroll
      for (int h = 0; h < 2; ++h) {
        const int row = lrow + h * 32;
#pragma unroll
        for (int j = 0; j < 8; ++j) tile[row][lcol + j] = s[h][j];
      }
      __syncthreads();
#pragma unroll
      for (int it = 0; it < 2; ++it) {
        const int idx = it * 256 + tid;
        const int dl = idx >> 3;          // mirror row offset (0..63)
        const int so = (idx & 7) * 8;     // mirror col chunk
        const int soct2 = SWZG ? (((idx & 7) ^ (dl & 7)) * 8) : so;
        union { short8 v; __hip_bfloat16 e8[8]; } o;
#pragma unroll
        for (int j = 0; j < 8; ++j) o.e8[j] = __float2bfloat16(tile[so + j][dl]);
        *(short8*)&Gb[(long)(c0 + qc + dl) * DIM + r0 + qr + soct2] = o.v;
      }
    }
  }
}

// ---------------- host launch ----------------------------------------------
extern "C" void kernel_launch(void* const* d_in, const int* in_sizes, int n_in,
                              void* d_out, int out_size, void* d_ws, size_t ws_size,
                              hipStream_t stream) {
  const float* X = (const float*)d_in[0];
  float* out = (float*)d_out;
  const long xtBytes = (long)BATCH * DIM * SEQ * 2;               // 33.5 MB
  const long gramBytes = (long)BATCH * DIM * DIM * 2;             // 4.2 MB
  const long partBytes = (long)BATCH * SPLITK * DIM * DIM * 2;    // 33.5 MB (bf16)
  __hip_bfloat16* Xt = (__hip_bfloat16*)d_out;
  __hip_bfloat16* gram = (__hip_bfloat16*)d_ws;

  const bool bigWs = ws_size >= (size_t)(gramBytes + xtBytes + partBytes);
  const bool midWs = ws_size >= (size_t)(gramBytes + xtBytes);
  __hip_bfloat16* Xb16 = midWs ? (__hip_bfloat16*)((char*)d_ws + gramBytes) : nullptr;

  // k1: Xt[b][d][s] (+ swizzled Xb16[b][s][d] if ws fits)
  transpose_cast_kernel<<<dim3(SEQ / 64, DIM / 64, BATCH), 256, 0, stream>>>(X, Xt, Xb16);

  // k2: split-8 gram partials (bf16), upper-triangle tiles only (symmetry)
  __hip_bfloat16* partials = bigWs
      ? (__hip_bfloat16*)((char*)d_ws + gramBytes + xtBytes)
      : (__hip_bfloat16*)((char*)d_out + xtBytes);
  gemm_bt_kernel<SPLITK, false, 2, __hip_bfloat16>
      <<<dim3(BATCH * SPLITK, 10, 1), 256, 0, stream>>>(
          nullptr, Xt, Xt, partials, SEQ, SEQ, SEQ, DIM,
          (long)DIM * SEQ, (long)DIM * SEQ, (long)DIM * DIM);

  // kr: triangle partials -> full gram (mirror off-diagonal tiles)
  if (midWs) {
    reduce_mirror_kernel<SPLITK, true><<<dim3(10, BATCH), 256, 0, stream>>>(
        partials, gram);
    // k3: 8-phase 256^2, one batch per XCD, 256 blocks = 1/CU
    gemm_8ph_kernel<<<dim3(256, 1, 1), 512, 0, stream>>>(Xb16, gram, out);
  } else {
    reduce_mirror_kernel<SPLITK, false><<<dim3(10, BATCH), 256, 0, stream>>>(
        partials, gram);
    gemm_bt_kernel<1, true, 1, float><<<dim3(128, 1, BATCH), 256, 0, stream>>>(
        X, nullptr, gram, out, DIM, DIM, DIM, DIM,
        (long)SEQ * DIM, (long)DIM * DIM, (long)SEQ * DIM);
  }
}